// Round 11
// baseline (493.554 us; speedup 1.0000x reference)
//
#include <hip/hip_runtime.h>

#define N_NODES 50000
#define N_EDGES 800000
#define D_IN 128
#define D_HID 256
#define D_OUT 256

#define SCAN_BLOCKS ((N_NODES + 255) / 256)  // 196
#define NXB ((N_NODES + 127) / 128)          // 391 row-panels
#define GEMM_GRID (NXB * 4)                  // 1564 blocks (4 col-tiles of 64)

using short8 = __attribute__((ext_vector_type(8))) short;
using f32x4  = __attribute__((ext_vector_type(4))) float;

__device__ inline unsigned short f2bf(float f) {
    unsigned u = __float_as_uint(f);
    u += 0x7fff + ((u >> 16) & 1);
    return (unsigned short)(u >> 16);
}
__device__ inline float bf2f(unsigned v16) {
    return __uint_as_float(v16 << 16);
}

// ---------------- CSR build ----------------

__global__ void hist_kernel(const int* __restrict__ dst, int* __restrict__ cnt) {
    int e = blockIdx.x * blockDim.x + threadIdx.x;
    if (e < N_EDGES) atomicAdd(&cnt[dst[e]], 1);
}

__global__ __launch_bounds__(256) void scan1_kernel(const int* __restrict__ cnt,
                                                    int* __restrict__ blocksum) {
    int i = blockIdx.x * 256 + threadIdx.x;
    int v = (i < N_NODES) ? cnt[i] : 0;
    int lane = threadIdx.x & 63, wid = threadIdx.x >> 6;
    for (int off = 32; off; off >>= 1) v += __shfl_down(v, off);
    __shared__ int ws[4];
    if (lane == 0) ws[wid] = v;
    __syncthreads();
    if (threadIdx.x == 0) blocksum[blockIdx.x] = ws[0] + ws[1] + ws[2] + ws[3];
}

__global__ __launch_bounds__(256) void scan2_kernel(const int* __restrict__ blocksum,
                                                    int* __restrict__ blockoff) {
    int tid = threadIdx.x;
    int lane = tid & 63, wid = tid >> 6;
    int v = (tid < SCAN_BLOCKS) ? blocksum[tid] : 0;
    int inc = v;
    for (int off = 1; off < 64; off <<= 1) {
        int u = __shfl_up(inc, off);
        if (lane >= off) inc += u;
    }
    __shared__ int ws[4];
    if (lane == 63) ws[wid] = inc;
    __syncthreads();
    int base = 0;
    for (int w = 0; w < wid; ++w) base += ws[w];
    if (tid < SCAN_BLOCKS) blockoff[tid] = base + inc - v;  // exclusive
}

__global__ __launch_bounds__(256) void scan3_kernel(const int* __restrict__ cnt,
                                                    const int* __restrict__ blockoff,
                                                    int* __restrict__ row_ptr,
                                                    int* __restrict__ cursor,
                                                    float* __restrict__ inv_deg) {
    int i = blockIdx.x * 256 + threadIdx.x;
    int c = (i < N_NODES) ? cnt[i] : 0;
    int lane = threadIdx.x & 63, wid = threadIdx.x >> 6;
    int inc = c;
    for (int off = 1; off < 64; off <<= 1) {
        int u = __shfl_up(inc, off);
        if (lane >= off) inc += u;
    }
    __shared__ int ws[4];
    if (lane == 63) ws[wid] = inc;
    __syncthreads();
    int base = blockoff[blockIdx.x];
    for (int w = 0; w < wid; ++w) base += ws[w];
    if (i < N_NODES) {
        int pos = base + inc - c;
        row_ptr[i] = pos;
        cursor[i] = pos;
        inv_deg[i] = 1.0f / (float)max(c, 1);
    }
    if (i == 0) row_ptr[N_NODES] = N_EDGES;
}

__global__ void fill_kernel(const int* __restrict__ src, const int* __restrict__ dst,
                            int* __restrict__ cursor, int* __restrict__ srcs) {
    int e = blockIdx.x * blockDim.x + threadIdx.x;
    if (e < N_EDGES) {
        int pos = atomicAdd(&cursor[dst[e]], 1);
        srcs[pos] = src[e];
    }
}

// ---------------- conversions ----------------

__global__ void convx_kernel(const float* __restrict__ x,
                             unsigned short* __restrict__ A1,
                             unsigned short* __restrict__ A2) {
    int idx = blockIdx.x * 256 + threadIdx.x;
    if (idx >= N_NODES * D_IN) return;
    int n = idx >> 7, k = idx & 127;
    unsigned short b = f2bf(x[idx]);
    A1[(long)n * 256 + k] = b;
    A2[(long)n * 640 + 512 + k] = b;
}

__global__ void wconv1_kernel(const float* __restrict__ Ws, const float* __restrict__ Wn,
                              unsigned short* __restrict__ Wt) {
    int j = blockIdx.x;
    for (int k = threadIdx.x; k < 256; k += 256) {
        float v = (k < 128) ? Ws[k * 256 + j] : Wn[(k - 128) * 256 + j];
        Wt[j * 256 + k] = f2bf(v);
    }
}

__global__ void wconv2_kernel(const float* __restrict__ Ws, const float* __restrict__ Wn,
                              const float* __restrict__ Wr,
                              unsigned short* __restrict__ Wt) {
    int j = blockIdx.x;
    for (int k = threadIdx.x; k < 640; k += 256) {
        float v = (k < 256) ? Ws[k * 256 + j]
                : (k < 512) ? Wn[(k - 256) * 256 + j]
                            : Wr[(k - 512) * 256 + j];
        Wt[j * 640 + k] = f2bf(v);
    }
}

// ---------------- mean aggregation ----------------

__global__ void agg1_kernel(const int* __restrict__ row_ptr,
                            const int* __restrict__ srcs,
                            const float* __restrict__ inv_deg,
                            unsigned short* __restrict__ A1) {
    int n = blockIdx.x;
    int tid = threadIdx.x;  // 128
    int beg = row_ptr[n], end = row_ptr[n + 1];
    float acc = 0.f;
    int e = beg;
    for (; e + 3 < end; e += 4) {
        int s0 = srcs[e], s1 = srcs[e + 1], s2 = srcs[e + 2], s3 = srcs[e + 3];
        unsigned v0 = A1[(long)s0 * 256 + tid];
        unsigned v1 = A1[(long)s1 * 256 + tid];
        unsigned v2 = A1[(long)s2 * 256 + tid];
        unsigned v3 = A1[(long)s3 * 256 + tid];
        acc += (bf2f(v0) + bf2f(v1)) + (bf2f(v2) + bf2f(v3));
    }
    for (; e < end; ++e) acc += bf2f((unsigned)A1[(long)srcs[e] * 256 + tid]);
    A1[(long)n * 256 + 128 + tid] = f2bf(acc * inv_deg[n]);
}

__global__ void agg2_kernel(unsigned short* __restrict__ A2,
                            const int* __restrict__ row_ptr,
                            const int* __restrict__ srcs,
                            const float* __restrict__ inv_deg) {
    int n = blockIdx.x;
    int tid = threadIdx.x;  // 128 threads, 2 cols each
    int beg = row_ptr[n], end = row_ptr[n + 1];
    float a0 = 0.f, a1 = 0.f;
    int e = beg;
    for (; e + 3 < end; e += 4) {
        int s0 = srcs[e], s1 = srcs[e + 1], s2 = srcs[e + 2], s3 = srcs[e + 3];
        unsigned v0 = ((const unsigned*)(A2 + (long)s0 * 640))[tid];
        unsigned v1 = ((const unsigned*)(A2 + (long)s1 * 640))[tid];
        unsigned v2 = ((const unsigned*)(A2 + (long)s2 * 640))[tid];
        unsigned v3 = ((const unsigned*)(A2 + (long)s3 * 640))[tid];
        a0 += (bf2f(v0 & 0xffffu) + bf2f(v1 & 0xffffu)) +
              (bf2f(v2 & 0xffffu) + bf2f(v3 & 0xffffu));
        a1 += (bf2f(v0 >> 16) + bf2f(v1 >> 16)) + (bf2f(v2 >> 16) + bf2f(v3 >> 16));
    }
    for (; e < end; ++e) {
        unsigned v = ((const unsigned*)(A2 + (long)srcs[e] * 640))[tid];
        a0 += bf2f(v & 0xffffu);
        a1 += bf2f(v >> 16);
    }
    float inv = inv_deg[n];
    unsigned o = (unsigned)f2bf(a0 * inv) | ((unsigned)f2bf(a1 * inv) << 16);
    ((unsigned*)(A2 + (long)n * 640 + 256))[tid] = o;
}

// ---------------- MFMA GEMM: LDS-staged B + chunk-pipelined A registers ------
// r10 post-mortem: VGPR=68 proved hipcc SANK the aA/aB prefetch loads to their
// use point, deleting the pipeline. Fix: __builtin_amdgcn_sched_barrier(0)
// after each prefetch-issue cluster pins the schedule (rule #18 fence). If the
// pin works, VGPR must rise to >=130 (checkable in counters).
// UNIFORM_A=true is the ablation probe: A-loads all hit row 0 (L1-broadcast,
// ~zero latency, identical instruction stream) -> separates latency-bound vs
// issue-bound for the unpinned 83us baseline.

template <int K, bool RELU, bool PIN, bool UNIFORM_A>
__global__ __launch_bounds__(256) void gemm_ldsb_kernel(
    const unsigned short* __restrict__ A, const unsigned short* __restrict__ Bt,
    const float* __restrict__ bias, unsigned short* __restrict__ out, int outStride) {
    constexpr int NC = K / 128;   // K-chunks of 128 (2 or 5)
    constexpr int LDSK = 132;     // 128 + 4 pad (shorts) -> conflict-free ds_read
    __shared__ unsigned short Blds[2][64][LDSK];

    int tid = threadIdx.x;
    int lane = tid & 63, w = tid >> 6;
    // bijective chunked block->XCD remap (keeps 4 col-tiles of one A-panel on
    // one XCD's L2; halved FETCH_SIZE in r8).
    int b = blockIdx.x;
    int xcd = b & 7, slot = b >> 3;
    int l = (xcd < 4) ? xcd * 196 + slot : 4 * 196 + (xcd - 4) * 195 + slot;
    int bx = l >> 2, by = l & 3;

    int rb = bx * 128 + w * 32;
    int cb = by * 64;
    int l15 = lane & 15;
    int kg = (lane >> 4) * 8;

    // A row pointers (2 row-frags per wave); OOB rows clamp to 0 (never stored)
    const unsigned short* pA[2];
#pragma unroll
    for (int i = 0; i < 2; ++i) {
        int r = UNIFORM_A ? 0 : (rb + 16 * i + l15);
        if (r >= N_NODES) r = 0;
        pA[i] = A + (long)r * K + kg;
    }
    // B staging: 64 cols x 128 k = 16 KB/chunk; 256 threads x 4 iters x 16 B.
    const unsigned short* pS[4];
    unsigned short* pW[4];
#pragma unroll
    for (int it = 0; it < 4; ++it) {
        int q = it * 256 + tid;
        int col = q >> 4, ck = q & 15;
        pS[it] = Bt + (long)(cb + col) * K + ck * 8;
        pW[it] = &Blds[0][col][ck * 8];
    }
    constexpr int BUFOFF = 64 * LDSK;

    f32x4 acc[2][4] = {};
    short8 st[4];
    short8 aA[8], aB[8];  // two chunk-sized A register buffers (static indexing only)

    auto stageIssue = [&](int cc) {
#pragma unroll
        for (int it = 0; it < 4; ++it) st[it] = *(const short8*)(pS[it] + cc * 128);
    };
    auto stageWrite = [&](int buf) {
#pragma unroll
        for (int it = 0; it < 4; ++it) *(short8*)(pW[it] + buf * BUFOFF) = st[it];
    };
    auto loadChunk = [&](short8 (&dst)[8], int cc) {
#pragma unroll
        for (int i = 0; i < 2; ++i)
#pragma unroll
            for (int t = 0; t < 4; ++t)
                dst[i * 4 + t] = *(const short8*)(pA[i] + (cc * 4 + t) * 32);
    };
    auto computeChunk = [&](const short8 (&areg)[8], int buf) {
        const unsigned short* Bb = &Blds[0][0][0] + buf * BUFOFF;
#pragma unroll
        for (int t = 0; t < 4; ++t) {
            short8 bfr[4];
#pragma unroll
            for (int j = 0; j < 4; ++j)
                bfr[j] = *(const short8*)(Bb + (16 * j + l15) * LDSK + t * 32 + kg);
#pragma unroll
            for (int i = 0; i < 2; ++i)
#pragma unroll
                for (int j = 0; j < 4; ++j)
                    acc[i][j] = __builtin_amdgcn_mfma_f32_16x16x32_bf16(
                        areg[i * 4 + t], bfr[j], acc[i][j], 0, 0, 0);
        }
    };

    // prologue: stage B chunk 0, load A chunk 0
    stageIssue(0);
    stageWrite(0);
    loadChunk(aA, 0);
    if (PIN) __builtin_amdgcn_sched_barrier(0);
    __syncthreads();

    int c = 0;
    while (c + 2 <= NC) {
        // chunk c (aA); prefetch c+1 (B-stage + aB)
        stageIssue(c + 1);
        loadChunk(aB, c + 1);
        if (PIN) __builtin_amdgcn_sched_barrier(0);  // forbid sinking loads past compute
        computeChunk(aA, c & 1);
        __syncthreads();
        stageWrite((c + 1) & 1);
        __syncthreads();
        // chunk c+1 (aB); prefetch c+2 (if any)
        if (c + 2 < NC) {
            stageIssue(c + 2);
            loadChunk(aA, c + 2);
            if (PIN) __builtin_amdgcn_sched_barrier(0);
        }
        computeChunk(aB, (c + 1) & 1);
        __syncthreads();
        if (c + 2 < NC) stageWrite((c + 2) & 1);
        __syncthreads();
        c += 2;
    }
    if (c < NC) computeChunk(aA, c & 1);  // odd-NC tail (chunk already prefetched)

    // C/D layout: col = lane&15, row = (lane>>4)*4 + reg   [m89-verified]
#pragma unroll
    for (int j = 0; j < 4; ++j) {
        int cc = cb + 16 * j + l15;
        float bv = bias[cc];
#pragma unroll
        for (int i = 0; i < 2; ++i) {
            int rbase = rb + 16 * i + (lane >> 4) * 4;
#pragma unroll
            for (int r = 0; r < 4; ++r) {
                int row = rbase + r;
                if (row < N_NODES) {
                    float v = acc[i][j][r] + bv;
                    if (RELU) v = fmaxf(v, 0.f);
                    out[(long)row * outStride + cc] = f2bf(v);
                }
            }
        }
    }
}

// ---------------- MLP head ----------------

__global__ __launch_bounds__(256) void head_kernel(const unsigned short* __restrict__ h2,
                                                   const float* __restrict__ Wmlp,
                                                   const float* __restrict__ bmlp,
                                                   float* __restrict__ out) {
    int n = blockIdx.x * 4 + (threadIdx.x >> 6);
    int lane = threadIdx.x & 63;
    const unsigned* p = (const unsigned*)(h2 + (long)n * 256 + lane * 4);
    unsigned v0 = p[0], v1 = p[1];
    float f0 = bf2f(v0 & 0xffffu), f1 = bf2f(v0 >> 16);
    float f2 = bf2f(v1 & 0xffffu), f3 = bf2f(v1 >> 16);
    int k = lane * 4;
    float p0 = f0 * Wmlp[k * 2]       + f1 * Wmlp[(k + 1) * 2]
             + f2 * Wmlp[(k + 2) * 2] + f3 * Wmlp[(k + 3) * 2];
    float p1 = f0 * Wmlp[k * 2 + 1]       + f1 * Wmlp[(k + 1) * 2 + 1]
             + f2 * Wmlp[(k + 2) * 2 + 1] + f3 * Wmlp[(k + 3) * 2 + 1];
    for (int off = 32; off; off >>= 1) {
        p0 += __shfl_down(p0, off);
        p1 += __shfl_down(p1, off);
    }
    if (lane == 0) {
        out[(long)n * 2]     = p0 + bmlp[0];
        out[(long)n * 2 + 1] = p1 + bmlp[1];
    }
}

// ---------------- launch ----------------

extern "C" void kernel_launch(void* const* d_in, const int* in_sizes, int n_in,
                              void* d_out, int out_size, void* d_ws, size_t ws_size,
                              hipStream_t stream) {
    const float* x    = (const float*)d_in[0];
    const int*   src  = (const int*)d_in[1];
    const int*   dst  = (const int*)d_in[2];
    const float* Ws1  = (const float*)d_in[3];
    const float* Wn1  = (const float*)d_in[4];
    const float* b1   = (const float*)d_in[5];
    const float* Ws2  = (const float*)d_in[6];
    const float* Wn2  = (const float*)d_in[7];
    const float* b2   = (const float*)d_in[8];
    const float* Wres = (const float*)d_in[9];
    const float* Wmlp = (const float*)d_in[10];
    const float* bmlp = (const float*)d_in[11];
    float* out = (float*)d_out;

    char* ws = (char*)d_ws;
    size_t off = 0;
    auto alloc = [&](size_t bytes) {
        void* p = ws + off;
        off += (bytes + 255) & ~(size_t)255;
        return p;
    };
    int*            cnt      = (int*)alloc((size_t)N_NODES * 4);
    int*            row_ptr  = (int*)alloc((size_t)(N_NODES + 1) * 4);
    int*            cursor   = (int*)alloc((size_t)N_NODES * 4);
    float*          inv_deg  = (float*)alloc((size_t)N_NODES * 4);
    int*            srcs     = (int*)alloc((size_t)N_EDGES * 4);
    int*            blocksum = (int*)alloc((size_t)SCAN_BLOCKS * 4);
    int*            blockoff = (int*)alloc((size_t)SCAN_BLOCKS * 4);
    unsigned short* A1       = (unsigned short*)alloc((size_t)N_NODES * 256 * 2);  // [x|agg1]; later h2
    unsigned short* A2       = (unsigned short*)alloc((size_t)N_NODES * 640 * 2);  // [h1|agg2|x]
    unsigned short* Wt1      = (unsigned short*)alloc((size_t)256 * 256 * 2);
    unsigned short* Wt2      = (unsigned short*)alloc((size_t)256 * 640 * 2);

    hipMemsetAsync(cnt, 0, (size_t)N_NODES * 4, stream);
    hist_kernel<<<(N_EDGES + 255) / 256, 256, 0, stream>>>(dst, cnt);
    scan1_kernel<<<SCAN_BLOCKS, 256, 0, stream>>>(cnt, blocksum);
    scan2_kernel<<<1, 256, 0, stream>>>(blocksum, blockoff);
    scan3_kernel<<<SCAN_BLOCKS, 256, 0, stream>>>(cnt, blockoff, row_ptr, cursor, inv_deg);
    fill_kernel<<<(N_EDGES + 255) / 256, 256, 0, stream>>>(src, dst, cursor, srcs);
    convx_kernel<<<(N_NODES * D_IN + 255) / 256, 256, 0, stream>>>(x, A1, A2);
    wconv1_kernel<<<256, 256, 0, stream>>>(Ws1, Wn1, Wt1);
    wconv2_kernel<<<256, 256, 0, stream>>>(Ws2, Wn2, Wres, Wt2);
    agg1_kernel<<<N_NODES, 128, 0, stream>>>(row_ptr, srcs, inv_deg, A1);

    // layer 1: h1 = relu([x|agg1] @ Wt1^T + b1) -> Acat2 cols [0,256)
    gemm_ldsb_kernel<256, true, true, false><<<GEMM_GRID, 256, 0, stream>>>(A1, Wt1, b1, A2, 640);
    agg2_kernel<<<N_NODES, 128, 0, stream>>>(A2, row_ptr, srcs, inv_deg);
    // layer 2: h2 = [h1|agg2|x] @ Wt2^T + b2 -> A1 (reused as h2 buffer, stride 256)
    gemm_ldsb_kernel<640, false, true, false><<<GEMM_GRID, 256, 0, stream>>>(A2, Wt2, b2, A1, 256);
    head_kernel<<<N_NODES / 4, 256, 0, stream>>>(A1, Wmlp, bmlp, out);

    // ---- ablation probe (runs after d_out is complete; writes to dead A1) ----
    // Unpinned r10 structure with UNIFORM_A: if ~25-40us -> old GEMM was
    // latency-bound; if ~80us -> issue/barrier-bound.
    gemm_ldsb_kernel<640, false, false, true><<<GEMM_GRID, 256, 0, stream>>>(A2, Wt2, b2, A1, 256);
}

// Round 13
// 378.659 us; speedup vs baseline: 1.3034x; 1.3034x over previous
//
#include <hip/hip_runtime.h>

#define N_NODES 50000
#define N_EDGES 800000
#define D_IN 128
#define D_HID 256
#define D_OUT 256

#define SCAN_BLOCKS ((N_NODES + 255) / 256)  // 196
#define NXB ((N_NODES + 127) / 128)          // 391 row-panels
#define M_PAD (NXB * 128)                    // 50048 (padded rows: staged, never stored)

using short8 = __attribute__((ext_vector_type(8))) short;
using f32x4  = __attribute__((ext_vector_type(4))) float;

__device__ inline unsigned short f2bf(float f) {
    unsigned u = __float_as_uint(f);
    u += 0x7fff + ((u >> 16) & 1);
    return (unsigned short)(u >> 16);
}
__device__ inline float bf2f(unsigned v16) {
    return __uint_as_float(v16 << 16);
}

__device__ inline void gload_lds16(const void* g, void* l) {
    __builtin_amdgcn_global_load_lds(
        (const __attribute__((address_space(1))) unsigned int*)g,
        (__attribute__((address_space(3))) unsigned int*)l, 16, 0, 0);
}

// ---------------- CSR build ----------------

__global__ void hist_kernel(const int* __restrict__ dst, int* __restrict__ cnt) {
    int e = blockIdx.x * blockDim.x + threadIdx.x;
    if (e < N_EDGES) atomicAdd(&cnt[dst[e]], 1);
}

__global__ __launch_bounds__(256) void scan1_kernel(const int* __restrict__ cnt,
                                                    int* __restrict__ blocksum) {
    int i = blockIdx.x * 256 + threadIdx.x;
    int v = (i < N_NODES) ? cnt[i] : 0;
    int lane = threadIdx.x & 63, wid = threadIdx.x >> 6;
    for (int off = 32; off; off >>= 1) v += __shfl_down(v, off);
    __shared__ int ws[4];
    if (lane == 0) ws[wid] = v;
    __syncthreads();
    if (threadIdx.x == 0) blocksum[blockIdx.x] = ws[0] + ws[1] + ws[2] + ws[3];
}

__global__ __launch_bounds__(256) void scan2_kernel(const int* __restrict__ blocksum,
                                                    int* __restrict__ blockoff) {
    int tid = threadIdx.x;
    int lane = tid & 63, wid = tid >> 6;
    int v = (tid < SCAN_BLOCKS) ? blocksum[tid] : 0;
    int inc = v;
    for (int off = 1; off < 64; off <<= 1) {
        int u = __shfl_up(inc, off);
        if (lane >= off) inc += u;
    }
    __shared__ int ws[4];
    if (lane == 63) ws[wid] = inc;
    __syncthreads();
    int base = 0;
    for (int w = 0; w < wid; ++w) base += ws[w];
    if (tid < SCAN_BLOCKS) blockoff[tid] = base + inc - v;  // exclusive
}

__global__ __launch_bounds__(256) void scan3_kernel(const int* __restrict__ cnt,
                                                    const int* __restrict__ blockoff,
                                                    int* __restrict__ row_ptr,
                                                    int* __restrict__ cursor,
                                                    float* __restrict__ inv_deg) {
    int i = blockIdx.x * 256 + threadIdx.x;
    int c = (i < N_NODES) ? cnt[i] : 0;
    int lane = threadIdx.x & 63, wid = threadIdx.x >> 6;
    int inc = c;
    for (int off = 1; off < 64; off <<= 1) {
        int u = __shfl_up(inc, off);
        if (lane >= off) inc += u;
    }
    __shared__ int ws[4];
    if (lane == 63) ws[wid] = inc;
    __syncthreads();
    int base = blockoff[blockIdx.x];
    for (int w = 0; w < wid; ++w) base += ws[w];
    if (i < N_NODES) {
        int pos = base + inc - c;
        row_ptr[i] = pos;
        cursor[i] = pos;
        inv_deg[i] = 1.0f / (float)max(c, 1);
    }
    if (i == 0) row_ptr[N_NODES] = N_EDGES;
}

__global__ void fill_kernel(const int* __restrict__ src, const int* __restrict__ dst,
                            int* __restrict__ cursor, int* __restrict__ srcs) {
    int e = blockIdx.x * blockDim.x + threadIdx.x;
    if (e < N_EDGES) {
        int pos = atomicAdd(&cursor[dst[e]], 1);
        srcs[pos] = src[e];
    }
}

// ---------------- conversions ----------------

__global__ void convx_kernel(const float* __restrict__ x,
                             unsigned short* __restrict__ A1,
                             unsigned short* __restrict__ A2) {
    int idx = blockIdx.x * 256 + threadIdx.x;
    if (idx >= N_NODES * D_IN) return;
    int n = idx >> 7, k = idx & 127;
    unsigned short b = f2bf(x[idx]);
    A1[(long)n * 256 + k] = b;
    A2[(long)n * 640 + 512 + k] = b;
}

__global__ void wconv1_kernel(const float* __restrict__ Ws, const float* __restrict__ Wn,
                              unsigned short* __restrict__ Wt) {
    int j = blockIdx.x;
    for (int k = threadIdx.x; k < 256; k += 256) {
        float v = (k < 128) ? Ws[k * 256 + j] : Wn[(k - 128) * 256 + j];
        Wt[j * 256 + k] = f2bf(v);
    }
}

__global__ void wconv2_kernel(const float* __restrict__ Ws, const float* __restrict__ Wn,
                              const float* __restrict__ Wr,
                              unsigned short* __restrict__ Wt) {
    int j = blockIdx.x;
    for (int k = threadIdx.x; k < 640; k += 256) {
        float v = (k < 256) ? Ws[k * 256 + j]
                : (k < 512) ? Wn[(k - 256) * 256 + j]
                            : Wr[(k - 512) * 256 + j];
        Wt[j * 640 + k] = f2bf(v);
    }
}

// ---------------- mean aggregation ----------------

__global__ void agg1_kernel(const int* __restrict__ row_ptr,
                            const int* __restrict__ srcs,
                            const float* __restrict__ inv_deg,
                            unsigned short* __restrict__ A1) {
    int n = blockIdx.x;
    int tid = threadIdx.x;  // 128
    int beg = row_ptr[n], end = row_ptr[n + 1];
    float acc = 0.f;
    int e = beg;
    for (; e + 3 < end; e += 4) {
        int s0 = srcs[e], s1 = srcs[e + 1], s2 = srcs[e + 2], s3 = srcs[e + 3];
        unsigned v0 = A1[(long)s0 * 256 + tid];
        unsigned v1 = A1[(long)s1 * 256 + tid];
        unsigned v2 = A1[(long)s2 * 256 + tid];
        unsigned v3 = A1[(long)s3 * 256 + tid];
        acc += (bf2f(v0) + bf2f(v1)) + (bf2f(v2) + bf2f(v3));
    }
    for (; e < end; ++e) acc += bf2f((unsigned)A1[(long)srcs[e] * 256 + tid]);
    A1[(long)n * 256 + 128 + tid] = f2bf(acc * inv_deg[n]);
}

__global__ void agg2_kernel(unsigned short* __restrict__ A2,
                            const int* __restrict__ row_ptr,
                            const int* __restrict__ srcs,
                            const float* __restrict__ inv_deg) {
    int n = blockIdx.x;
    int tid = threadIdx.x;  // 128 threads, 2 cols each
    int beg = row_ptr[n], end = row_ptr[n + 1];
    float a0 = 0.f, a1 = 0.f;
    int e = beg;
    for (; e + 3 < end; e += 4) {
        int s0 = srcs[e], s1 = srcs[e + 1], s2 = srcs[e + 2], s3 = srcs[e + 3];
        unsigned v0 = ((const unsigned*)(A2 + (long)s0 * 640))[tid];
        unsigned v1 = ((const unsigned*)(A2 + (long)s1 * 640))[tid];
        unsigned v2 = ((const unsigned*)(A2 + (long)s2 * 640))[tid];
        unsigned v3 = ((const unsigned*)(A2 + (long)s3 * 640))[tid];
        a0 += (bf2f(v0 & 0xffffu) + bf2f(v1 & 0xffffu)) +
              (bf2f(v2 & 0xffffu) + bf2f(v3 & 0xffffu));
        a1 += (bf2f(v0 >> 16) + bf2f(v1 >> 16)) + (bf2f(v2 >> 16) + bf2f(v3 >> 16));
    }
    for (; e < end; ++e) {
        unsigned v = ((const unsigned*)(A2 + (long)srcs[e] * 640))[tid];
        a0 += bf2f(v & 0xffffu);
        a1 += bf2f(v >> 16);
    }
    float inv = inv_deg[n];
    unsigned o = (unsigned)f2bf(a0 * inv) | ((unsigned)f2bf(a1 * inv) << 16);
    ((unsigned*)(A2 + (long)n * 640 + 256))[tid] = o;
}

// ---------------- m97-structure MFMA GEMM ----------------
// r11 ablation: UNIFORM_A probe == real (84us) -> NOT A-latency-bound; my
// hand-rolled reg pipelines never materialized (VGPR 68/84). Pivot to the
// HW-verified m97 template: global_load_lds width-16 stages BOTH 128x32
// A-tile and 128x32 B-tile into LDS each K-step; 4 waves x 64x64 quadrants;
// 2 barriers/step; compiler's counted-lgkmcnt ds_read->MFMA scheduling.
// A is [M_PAD][K] (padded rows staged but never stored). Bt is [256][K].

template <int K, bool RELU>
__global__ __launch_bounds__(256) void gemm97_kernel(
    const unsigned short* __restrict__ A, const unsigned short* __restrict__ Bt,
    const float* __restrict__ bias, unsigned short* __restrict__ out, int outStride) {
    __shared__ unsigned short As[128 * 32];  // [row][k] linear, 8 KB
    __shared__ unsigned short Bs[128 * 32];  // [col][k] linear, 8 KB

    int tid = threadIdx.x;
    int lane = tid & 63, w = tid >> 6;

    // bijective chunked block->XCD remap (NWG = NXB*2 = 782)
    constexpr int NWG = NXB * 2;
    constexpr int Q = NWG / 8, R = NWG % 8;
    int b = blockIdx.x;
    int xcd = b & 7, slot = b >> 3;
    int l = (xcd < R) ? xcd * (Q + 1) + slot : R * (Q + 1) + (xcd - R) * Q + slot;
    int bx = l >> 1, by = l & 1;

    int row0 = bx * 128, col0 = by * 128;
    int wr = (w >> 1) * 64, wc = (w & 1) * 64;  // wave quadrant within tile
    int l15 = lane & 15, kg = (lane >> 4) * 8;

    f32x4 acc[4][4] = {};

    // staging element index per (issue i, wave w, lane): e = (i*4+w)*64+lane;
    // covers 512 x 16B = 8KB; r=e>>2 (row/col), c8=e&3 (k-subchunk of 8)
    int e0 = w * 64 + lane;       // issue 0
    int e1 = 256 + e0;            // issue 1
    int r0 = e0 >> 2, c80 = e0 & 3;
    int r1 = e1 >> 2, c81 = e1 & 3;

    const unsigned short* gA0 = A + (long)(row0 + r0) * K + c80 * 8;
    const unsigned short* gA1 = A + (long)(row0 + r1) * K + c81 * 8;
    const unsigned short* gB0 = Bt + (long)(col0 + r0) * K + c80 * 8;
    const unsigned short* gB1 = Bt + (long)(col0 + r1) * K + c81 * 8;
    unsigned short* lA0 = &As[e0 * 8];
    unsigned short* lA1 = &As[e1 * 8];
    unsigned short* lB0 = &Bs[e0 * 8];
    unsigned short* lB1 = &Bs[e1 * 8];

    for (int kc = 0; kc < K; kc += 32) {
        gload_lds16(gA0 + kc, lA0);
        gload_lds16(gA1 + kc, lA1);
        gload_lds16(gB0 + kc, lB0);
        gload_lds16(gB1 + kc, lB1);
        __syncthreads();  // drains vmcnt -> tiles resident

        short8 a[4], bq[4];
#pragma unroll
        for (int i = 0; i < 4; ++i) {
            a[i]  = *(const short8*)(&As[(wr + 16 * i + l15) * 32 + kg]);
            bq[i] = *(const short8*)(&Bs[(wc + 16 * i + l15) * 32 + kg]);
        }
#pragma unroll
        for (int i = 0; i < 4; ++i)
#pragma unroll
            for (int j = 0; j < 4; ++j)
                acc[i][j] = __builtin_amdgcn_mfma_f32_16x16x32_bf16(a[i], bq[j], acc[i][j], 0, 0, 0);
        __syncthreads();  // LDS reusable next step
    }

    // C/D layout: col = lane&15, row = (lane>>4)*4 + reg   [m89-verified]
#pragma unroll
    for (int j = 0; j < 4; ++j) {
        int c = col0 + wc + 16 * j + l15;
        float bv = bias[c];
#pragma unroll
        for (int i = 0; i < 4; ++i) {
            int rbase = row0 + wr + 16 * i + (lane >> 4) * 4;
#pragma unroll
            for (int r = 0; r < 4; ++r) {
                int row = rbase + r;
                if (row < N_NODES) {
                    float v = acc[i][j][r] + bv;
                    if (RELU) v = fmaxf(v, 0.f);
                    out[(long)row * outStride + c] = f2bf(v);
                }
            }
        }
    }
}

// ---------------- MLP head ----------------

__global__ __launch_bounds__(256) void head_kernel(const unsigned short* __restrict__ h2,
                                                   const float* __restrict__ Wmlp,
                                                   const float* __restrict__ bmlp,
                                                   float* __restrict__ out) {
    int n = blockIdx.x * 4 + (threadIdx.x >> 6);
    int lane = threadIdx.x & 63;
    const unsigned* p = (const unsigned*)(h2 + (long)n * 256 + lane * 4);
    unsigned v0 = p[0], v1 = p[1];
    float f0 = bf2f(v0 & 0xffffu), f1 = bf2f(v0 >> 16);
    float f2 = bf2f(v1 & 0xffffu), f3 = bf2f(v1 >> 16);
    int k = lane * 4;
    float p0 = f0 * Wmlp[k * 2]       + f1 * Wmlp[(k + 1) * 2]
             + f2 * Wmlp[(k + 2) * 2] + f3 * Wmlp[(k + 3) * 2];
    float p1 = f0 * Wmlp[k * 2 + 1]       + f1 * Wmlp[(k + 1) * 2 + 1]
             + f2 * Wmlp[(k + 2) * 2 + 1] + f3 * Wmlp[(k + 3) * 2 + 1];
    for (int off = 32; off; off >>= 1) {
        p0 += __shfl_down(p0, off);
        p1 += __shfl_down(p1, off);
    }
    if (lane == 0) {
        out[(long)n * 2]     = p0 + bmlp[0];
        out[(long)n * 2 + 1] = p1 + bmlp[1];
    }
}

// ---------------- launch ----------------

extern "C" void kernel_launch(void* const* d_in, const int* in_sizes, int n_in,
                              void* d_out, int out_size, void* d_ws, size_t ws_size,
                              hipStream_t stream) {
    const float* x    = (const float*)d_in[0];
    const int*   src  = (const int*)d_in[1];
    const int*   dst  = (const int*)d_in[2];
    const float* Ws1  = (const float*)d_in[3];
    const float* Wn1  = (const float*)d_in[4];
    const float* b1   = (const float*)d_in[5];
    const float* Ws2  = (const float*)d_in[6];
    const float* Wn2  = (const float*)d_in[7];
    const float* b2   = (const float*)d_in[8];
    const float* Wres = (const float*)d_in[9];
    const float* Wmlp = (const float*)d_in[10];
    const float* bmlp = (const float*)d_in[11];
    float* out = (float*)d_out;

    char* ws = (char*)d_ws;
    size_t off = 0;
    auto alloc = [&](size_t bytes) {
        void* p = ws + off;
        off += (bytes + 255) & ~(size_t)255;
        return p;
    };
    int*            cnt      = (int*)alloc((size_t)N_NODES * 4);
    int*            row_ptr  = (int*)alloc((size_t)(N_NODES + 1) * 4);
    int*            cursor   = (int*)alloc((size_t)N_NODES * 4);
    float*          inv_deg  = (float*)alloc((size_t)N_NODES * 4);
    int*            srcs     = (int*)alloc((size_t)N_EDGES * 4);
    int*            blocksum = (int*)alloc((size_t)SCAN_BLOCKS * 4);
    int*            blockoff = (int*)alloc((size_t)SCAN_BLOCKS * 4);
    // padded to M_PAD rows: gemm staging reads rows [50000,50048) (0xAA junk,
    // never stored)
    unsigned short* A1       = (unsigned short*)alloc((size_t)M_PAD * 256 * 2);  // [x|agg1]; later h2
    unsigned short* A2       = (unsigned short*)alloc((size_t)M_PAD * 640 * 2);  // [h1|agg2|x]
    unsigned short* Wt1      = (unsigned short*)alloc((size_t)256 * 256 * 2);
    unsigned short* Wt2      = (unsigned short*)alloc((size_t)256 * 640 * 2);

    hipMemsetAsync(cnt, 0, (size_t)N_NODES * 4, stream);
    hist_kernel<<<(N_EDGES + 255) / 256, 256, 0, stream>>>(dst, cnt);
    scan1_kernel<<<SCAN_BLOCKS, 256, 0, stream>>>(cnt, blocksum);
    scan2_kernel<<<1, 256, 0, stream>>>(blocksum, blockoff);
    scan3_kernel<<<SCAN_BLOCKS, 256, 0, stream>>>(cnt, blockoff, row_ptr, cursor, inv_deg);
    fill_kernel<<<(N_EDGES + 255) / 256, 256, 0, stream>>>(src, dst, cursor, srcs);
    convx_kernel<<<(N_NODES * D_IN + 255) / 256, 256, 0, stream>>>(x, A1, A2);
    wconv1_kernel<<<256, 256, 0, stream>>>(Ws1, Wn1, Wt1);
    wconv2_kernel<<<256, 256, 0, stream>>>(Ws2, Wn2, Wres, Wt2);
    agg1_kernel<<<N_NODES, 128, 0, stream>>>(row_ptr, srcs, inv_deg, A1);

    // layer 1: h1 = relu([x|agg1] @ Wt1^T + b1) -> Acat2 cols [0,256)
    gemm97_kernel<256, true><<<NXB * 2, 256, 0, stream>>>(A1, Wt1, b1, A2, 640);
    agg2_kernel<<<N_NODES, 128, 0, stream>>>(A2, row_ptr, srcs, inv_deg);
    // layer 2: h2 = [h1|agg2|x] @ Wt2^T + b2 -> A1 (reused as h2 buffer, stride 256)
    gemm97_kernel<640, false><<<NXB * 2, 256, 0, stream>>>(A2, Wt2, b2, A1, 256);
    head_kernel<<<N_NODES / 4, 256, 0, stream>>>(A1, Wmlp, bmlp, out);
}

// Round 15
// 359.214 us; speedup vs baseline: 1.3740x; 1.0541x over previous
//
#include <hip/hip_runtime.h>

#define N_NODES 50000
#define N_EDGES 800000
#define D_IN 128
#define D_HID 256
#define D_OUT 256

#define SCAN_BLOCKS ((N_NODES + 255) / 256)  // 196
#define NXB ((N_NODES + 127) / 128)          // 391 row-panels
#define M_PAD (NXB * 128)                    // 50048 (padded rows: staged, never stored)

using short8 = __attribute__((ext_vector_type(8))) short;
using f32x4  = __attribute__((ext_vector_type(4))) float;

__device__ inline unsigned short f2bf(float f) {
    unsigned u = __float_as_uint(f);
    u += 0x7fff + ((u >> 16) & 1);
    return (unsigned short)(u >> 16);
}
__device__ inline float bf2f(unsigned v16) {
    return __uint_as_float(v16 << 16);
}

__device__ inline void gload_lds16(const void* g, void* l) {
    __builtin_amdgcn_global_load_lds(
        (const __attribute__((address_space(1))) unsigned int*)g,
        (__attribute__((address_space(3))) unsigned int*)l, 16, 0, 0);
}

// ---------------- CSR build ----------------

__global__ void hist_kernel(const int* __restrict__ dst, int* __restrict__ cnt) {
    int e = blockIdx.x * blockDim.x + threadIdx.x;
    if (e < N_EDGES) atomicAdd(&cnt[dst[e]], 1);
}

__global__ __launch_bounds__(256) void scan1_kernel(const int* __restrict__ cnt,
                                                    int* __restrict__ blocksum) {
    int i = blockIdx.x * 256 + threadIdx.x;
    int v = (i < N_NODES) ? cnt[i] : 0;
    int lane = threadIdx.x & 63, wid = threadIdx.x >> 6;
    for (int off = 32; off; off >>= 1) v += __shfl_down(v, off);
    __shared__ int ws[4];
    if (lane == 0) ws[wid] = v;
    __syncthreads();
    if (threadIdx.x == 0) blocksum[blockIdx.x] = ws[0] + ws[1] + ws[2] + ws[3];
}

__global__ __launch_bounds__(256) void scan2_kernel(const int* __restrict__ blocksum,
                                                    int* __restrict__ blockoff) {
    int tid = threadIdx.x;
    int lane = tid & 63, wid = tid >> 6;
    int v = (tid < SCAN_BLOCKS) ? blocksum[tid] : 0;
    int inc = v;
    for (int off = 1; off < 64; off <<= 1) {
        int u = __shfl_up(inc, off);
        if (lane >= off) inc += u;
    }
    __shared__ int ws[4];
    if (lane == 63) ws[wid] = inc;
    __syncthreads();
    int base = 0;
    for (int w = 0; w < wid; ++w) base += ws[w];
    if (tid < SCAN_BLOCKS) blockoff[tid] = base + inc - v;  // exclusive
}

__global__ __launch_bounds__(256) void scan3_kernel(const int* __restrict__ cnt,
                                                    const int* __restrict__ blockoff,
                                                    int* __restrict__ row_ptr,
                                                    int* __restrict__ cursor,
                                                    float* __restrict__ inv_deg) {
    int i = blockIdx.x * 256 + threadIdx.x;
    int c = (i < N_NODES) ? cnt[i] : 0;
    int lane = threadIdx.x & 63, wid = threadIdx.x >> 6;
    int inc = c;
    for (int off = 1; off < 64; off <<= 1) {
        int u = __shfl_up(inc, off);
        if (lane >= off) inc += u;
    }
    __shared__ int ws[4];
    if (lane == 63) ws[wid] = inc;
    __syncthreads();
    int base = blockoff[blockIdx.x];
    for (int w = 0; w < wid; ++w) base += ws[w];
    if (i < N_NODES) {
        int pos = base + inc - c;
        row_ptr[i] = pos;
        cursor[i] = pos;
        inv_deg[i] = 1.0f / (float)max(c, 1);
    }
    if (i == 0) row_ptr[N_NODES] = N_EDGES;
}

__global__ void fill_kernel(const int* __restrict__ src, const int* __restrict__ dst,
                            int* __restrict__ cursor, int* __restrict__ srcs) {
    int e = blockIdx.x * blockDim.x + threadIdx.x;
    if (e < N_EDGES) {
        int pos = atomicAdd(&cursor[dst[e]], 1);
        srcs[pos] = src[e];
    }
}

// ---------------- conversions ----------------

__global__ void convx_kernel(const float* __restrict__ x,
                             unsigned short* __restrict__ A1,
                             unsigned short* __restrict__ A2) {
    int idx = blockIdx.x * 256 + threadIdx.x;
    if (idx >= N_NODES * D_IN) return;
    int n = idx >> 7, k = idx & 127;
    unsigned short b = f2bf(x[idx]);
    A1[(long)n * 256 + k] = b;
    A2[(long)n * 640 + 512 + k] = b;
}

__global__ void wconv1_kernel(const float* __restrict__ Ws, const float* __restrict__ Wn,
                              unsigned short* __restrict__ Wt) {
    int j = blockIdx.x;
    for (int k = threadIdx.x; k < 256; k += 256) {
        float v = (k < 128) ? Ws[k * 256 + j] : Wn[(k - 128) * 256 + j];
        Wt[j * 256 + k] = f2bf(v);
    }
}

__global__ void wconv2_kernel(const float* __restrict__ Ws, const float* __restrict__ Wn,
                              const float* __restrict__ Wr,
                              unsigned short* __restrict__ Wt) {
    int j = blockIdx.x;
    for (int k = threadIdx.x; k < 640; k += 256) {
        float v = (k < 256) ? Ws[k * 256 + j]
                : (k < 512) ? Wn[(k - 256) * 256 + j]
                            : Wr[(k - 512) * 256 + j];
        Wt[j * 640 + k] = f2bf(v);
    }
}

// ---------------- mean aggregation ----------------

__global__ void agg1_kernel(const int* __restrict__ row_ptr,
                            const int* __restrict__ srcs,
                            const float* __restrict__ inv_deg,
                            unsigned short* __restrict__ A1) {
    int n = blockIdx.x;
    int tid = threadIdx.x;  // 128
    int beg = row_ptr[n], end = row_ptr[n + 1];
    float acc = 0.f;
    int e = beg;
    for (; e + 3 < end; e += 4) {
        int s0 = srcs[e], s1 = srcs[e + 1], s2 = srcs[e + 2], s3 = srcs[e + 3];
        unsigned v0 = A1[(long)s0 * 256 + tid];
        unsigned v1 = A1[(long)s1 * 256 + tid];
        unsigned v2 = A1[(long)s2 * 256 + tid];
        unsigned v3 = A1[(long)s3 * 256 + tid];
        acc += (bf2f(v0) + bf2f(v1)) + (bf2f(v2) + bf2f(v3));
    }
    for (; e < end; ++e) acc += bf2f((unsigned)A1[(long)srcs[e] * 256 + tid]);
    A1[(long)n * 256 + 128 + tid] = f2bf(acc * inv_deg[n]);
}

__global__ void agg2_kernel(unsigned short* __restrict__ A2,
                            const int* __restrict__ row_ptr,
                            const int* __restrict__ srcs,
                            const float* __restrict__ inv_deg) {
    int n = blockIdx.x;
    int tid = threadIdx.x;  // 128 threads, 2 cols each
    int beg = row_ptr[n], end = row_ptr[n + 1];
    float a0 = 0.f, a1 = 0.f;
    int e = beg;
    for (; e + 3 < end; e += 4) {
        int s0 = srcs[e], s1 = srcs[e + 1], s2 = srcs[e + 2], s3 = srcs[e + 3];
        unsigned v0 = ((const unsigned*)(A2 + (long)s0 * 640))[tid];
        unsigned v1 = ((const unsigned*)(A2 + (long)s1 * 640))[tid];
        unsigned v2 = ((const unsigned*)(A2 + (long)s2 * 640))[tid];
        unsigned v3 = ((const unsigned*)(A2 + (long)s3 * 640))[tid];
        a0 += (bf2f(v0 & 0xffffu) + bf2f(v1 & 0xffffu)) +
              (bf2f(v2 & 0xffffu) + bf2f(v3 & 0xffffu));
        a1 += (bf2f(v0 >> 16) + bf2f(v1 >> 16)) + (bf2f(v2 >> 16) + bf2f(v3 >> 16));
    }
    for (; e < end; ++e) {
        unsigned v = ((const unsigned*)(A2 + (long)srcs[e] * 640))[tid];
        a0 += bf2f(v & 0xffffu);
        a1 += bf2f(v >> 16);
    }
    float inv = inv_deg[n];
    unsigned o = (unsigned)f2bf(a0 * inv) | ((unsigned)f2bf(a1 * inv) << 16);
    ((unsigned*)(A2 + (long)n * 640 + 256))[tid] = o;
}

// ---------------- m97-structure MFMA GEMM, v2 ----------------
// r13 counters: bank-conflict 2.0e6 (8-way on 64B-row ds_read), WRITE 61MB
// (2.4x write-amp), 20 vmcnt drains. This version:
//  (a) BK=64 (half the drains, 8 outstanding gloads/thread/drain, 32KB LDS);
//  (b) XOR-swizzle, both-sides (rule #21): LDS dest stays linear (gload_lds
//      constraint); the GLOBAL source k-slot is pre-permuted s^=(r&7) and the
//      ds_read applies the same XOR -> 16-way conflict becomes 2-way (free);
//  (c) HEAD=true fuses the MLP head into the epilogue: h2 never hits memory,
//      partial (row x 2) dots reduced over 16 lanes then f32-atomicAdd into
//      memset-zeroed d_out; b2 folded per-col, bmlp added by (by==0,wc==0).

template <int K, bool RELU, bool HEAD>
__global__ __launch_bounds__(256) void gemm97_kernel(
    const unsigned short* __restrict__ A, const unsigned short* __restrict__ Bt,
    const float* __restrict__ bias, unsigned short* __restrict__ out, int outStride,
    const float* __restrict__ Wmlp, const float* __restrict__ bmlp,
    float* __restrict__ outF) {
    __shared__ unsigned short As[128 * 64];  // 16 KB, [row][k-slot swizzled]
    __shared__ unsigned short Bs[128 * 64];  // 16 KB

    int tid = threadIdx.x;
    int lane = tid & 63, w = tid >> 6;

    // bijective chunked block->XCD remap (NWG = NXB*2 = 782)
    constexpr int NWG = NXB * 2;
    constexpr int Q = NWG / 8, R = NWG % 8;
    int b = blockIdx.x;
    int xcd = b & 7, slot = b >> 3;
    int l = (xcd < R) ? xcd * (Q + 1) + slot : R * (Q + 1) + (xcd - R) * Q + slot;
    int bx = l >> 1, by = l & 1;

    int row0 = bx * 128, col0 = by * 128;
    int wr = (w >> 1) * 64, wc = (w & 1) * 64;
    int l15 = lane & 15, g = lane >> 4;

    f32x4 acc[4][4] = {};

    // staging: 1024 x 16B per matrix; thread q-th element e=q*256+tid;
    // LDS dest linear (e*16); global source k-slot pre-swizzled s^(r&7)
    const unsigned short* gA[4];
    const unsigned short* gB[4];
    unsigned short* lA[4];
    unsigned short* lB[4];
#pragma unroll
    for (int q = 0; q < 4; ++q) {
        int e = q * 256 + tid;
        int r = e >> 3, s = e & 7;
        int ks = s ^ (r & 7);
        gA[q] = A + (long)(row0 + r) * K + ks * 8;
        gB[q] = Bt + (long)(col0 + r) * K + ks * 8;
        lA[q] = &As[e * 8];
        lB[q] = &Bs[e * 8];
    }
    // read-side swizzled slot: logical slot L = t*4+g, physical = L ^ (l15&7)
    int p0s = (0 * 4 + g) ^ (l15 & 7);  // t=0
    int p1s = (1 * 4 + g) ^ (l15 & 7);  // t=1

    for (int kc = 0; kc < K; kc += 64) {
#pragma unroll
        for (int q = 0; q < 4; ++q) gload_lds16(gA[q] + kc, lA[q]);
#pragma unroll
        for (int q = 0; q < 4; ++q) gload_lds16(gB[q] + kc, lB[q]);
        __syncthreads();  // drain -> both 64-wide tiles resident

#pragma unroll
        for (int t = 0; t < 2; ++t) {
            int ps = t ? p1s : p0s;
            short8 a[4], bq[4];
#pragma unroll
            for (int i = 0; i < 4; ++i) {
                int ra = wr + 16 * i + l15;
                int rbq = wc + 16 * i + l15;
                a[i]  = *(const short8*)(&As[ra * 64 + ps * 8]);
                bq[i] = *(const short8*)(&Bs[rbq * 64 + ps * 8]);
            }
#pragma unroll
            for (int i = 0; i < 4; ++i)
#pragma unroll
                for (int j = 0; j < 4; ++j)
                    acc[i][j] = __builtin_amdgcn_mfma_f32_16x16x32_bf16(a[i], bq[j], acc[i][j], 0, 0, 0);
        }
        __syncthreads();
    }

    if (!HEAD) {
        // C/D layout: col = lane&15, row = (lane>>4)*4 + reg   [m89-verified]
#pragma unroll
        for (int j = 0; j < 4; ++j) {
            int c = col0 + wc + 16 * j + l15;
            float bv = bias[c];
#pragma unroll
            for (int i = 0; i < 4; ++i) {
                int rbase = row0 + wr + 16 * i + g * 4;
#pragma unroll
                for (int r = 0; r < 4; ++r) {
                    int row = rbase + r;
                    if (row < N_NODES) {
                        float v = acc[i][j][r] + bv;
                        if (RELU) v = fmaxf(v, 0.f);
                        out[(long)row * outStride + c] = f2bf(v);
                    }
                }
            }
        }
    } else {
        // fused head: h2[row][c] = acc + b2[c]; out[row][:2] += h2 . Wmlp
        float bv[4], wm0[4], wm1[4];
#pragma unroll
        for (int j = 0; j < 4; ++j) {
            int c = col0 + wc + 16 * j + l15;
            bv[j] = bias[c];
            wm0[j] = Wmlp[c * 2];
            wm1[j] = Wmlp[c * 2 + 1];
        }
        bool lead = (by == 0) && (wc == 0);
        float bm0 = bmlp[0], bm1 = bmlp[1];
#pragma unroll
        for (int i = 0; i < 4; ++i) {
            int rbase = row0 + wr + 16 * i + g * 4;
#pragma unroll
            for (int r = 0; r < 4; ++r) {
                float s0 = 0.f, s1 = 0.f;
#pragma unroll
                for (int j = 0; j < 4; ++j) {
                    float h = acc[i][j][r] + bv[j];
                    s0 += h * wm0[j];
                    s1 += h * wm1[j];
                }
                // reduce over the 16 lanes (l15) sharing this row
                for (int off = 1; off < 16; off <<= 1) {
                    s0 += __shfl_xor(s0, off);
                    s1 += __shfl_xor(s1, off);
                }
                int row = rbase + r;
                if (l15 == 0 && row < N_NODES) {
                    atomicAdd(&outF[(long)row * 2],     s0 + (lead ? bm0 : 0.f));
                    atomicAdd(&outF[(long)row * 2 + 1], s1 + (lead ? bm1 : 0.f));
                }
            }
        }
    }
}

// ---------------- launch ----------------

extern "C" void kernel_launch(void* const* d_in, const int* in_sizes, int n_in,
                              void* d_out, int out_size, void* d_ws, size_t ws_size,
                              hipStream_t stream) {
    const float* x    = (const float*)d_in[0];
    const int*   src  = (const int*)d_in[1];
    const int*   dst  = (const int*)d_in[2];
    const float* Ws1  = (const float*)d_in[3];
    const float* Wn1  = (const float*)d_in[4];
    const float* b1   = (const float*)d_in[5];
    const float* Ws2  = (const float*)d_in[6];
    const float* Wn2  = (const float*)d_in[7];
    const float* b2   = (const float*)d_in[8];
    const float* Wres = (const float*)d_in[9];
    const float* Wmlp = (const float*)d_in[10];
    const float* bmlp = (const float*)d_in[11];
    float* out = (float*)d_out;

    char* ws = (char*)d_ws;
    size_t off = 0;
    auto alloc = [&](size_t bytes) {
        void* p = ws + off;
        off += (bytes + 255) & ~(size_t)255;
        return p;
    };
    int*            cnt      = (int*)alloc((size_t)N_NODES * 4);
    int*            row_ptr  = (int*)alloc((size_t)(N_NODES + 1) * 4);
    int*            cursor   = (int*)alloc((size_t)N_NODES * 4);
    float*          inv_deg  = (float*)alloc((size_t)N_NODES * 4);
    int*            srcs     = (int*)alloc((size_t)N_EDGES * 4);
    int*            blocksum = (int*)alloc((size_t)SCAN_BLOCKS * 4);
    int*            blockoff = (int*)alloc((size_t)SCAN_BLOCKS * 4);
    // padded to M_PAD rows: gemm staging reads rows [50000,50048) (0xAA junk,
    // never stored)
    unsigned short* A1       = (unsigned short*)alloc((size_t)M_PAD * 256 * 2);  // [x|agg1]
    unsigned short* A2       = (unsigned short*)alloc((size_t)M_PAD * 640 * 2);  // [h1|agg2|x]
    unsigned short* Wt1      = (unsigned short*)alloc((size_t)256 * 256 * 2);
    unsigned short* Wt2      = (unsigned short*)alloc((size_t)256 * 640 * 2);

    hipMemsetAsync(cnt, 0, (size_t)N_NODES * 4, stream);
    hipMemsetAsync(out, 0, (size_t)N_NODES * 2 * 4, stream);  // fused head accumulates
    hist_kernel<<<(N_EDGES + 255) / 256, 256, 0, stream>>>(dst, cnt);
    scan1_kernel<<<SCAN_BLOCKS, 256, 0, stream>>>(cnt, blocksum);
    scan2_kernel<<<1, 256, 0, stream>>>(blocksum, blockoff);
    scan3_kernel<<<SCAN_BLOCKS, 256, 0, stream>>>(cnt, blockoff, row_ptr, cursor, inv_deg);
    fill_kernel<<<(N_EDGES + 255) / 256, 256, 0, stream>>>(src, dst, cursor, srcs);
    convx_kernel<<<(N_NODES * D_IN + 255) / 256, 256, 0, stream>>>(x, A1, A2);
    wconv1_kernel<<<256, 256, 0, stream>>>(Ws1, Wn1, Wt1);
    wconv2_kernel<<<256, 256, 0, stream>>>(Ws2, Wn2, Wres, Wt2);
    agg1_kernel<<<N_NODES, 128, 0, stream>>>(row_ptr, srcs, inv_deg, A1);

    // layer 1: h1 = relu([x|agg1] @ Wt1^T + b1) -> Acat2 cols [0,256)
    gemm97_kernel<256, true, false><<<NXB * 2, 256, 0, stream>>>(
        A1, Wt1, b1, A2, 640, nullptr, nullptr, nullptr);
    agg2_kernel<<<N_NODES, 128, 0, stream>>>(A2, row_ptr, srcs, inv_deg);
    // layer 2 + fused MLP head: out += ([h1|agg2|x] @ Wt2^T + b2) @ Wmlp + bmlp
    gemm97_kernel<640, false, true><<<NXB * 2, 256, 0, stream>>>(
        A2, Wt2, b2, nullptr, 0, Wmlp, bmlp, out);
}